// Round 1
// baseline (451.481 us; speedup 1.0000x reference)
//
#include <hip/hip_runtime.h>
#include <hip/hip_bf16.h>

// QLoRA rank-2 fused kernel.
// out[row, d] = 0.5 * b_scale[d] * ( h0*b_q[d,0] + h1*b_q[d,1] )
//   where h_r = a_scale[r] * sum_d' x[row, d'] * a_q[r, d']
//
// Shapes: x [16384, 4096] fp32, a_q [2,4096] int32, a_scale [2] fp32,
//         b_q [4096,2] int32, b_scale [4096] fp32, out [16384, 4096] fp32.
// One 256-thread block per row; each thread owns 16 elements (4x float4).

#define QL_D 4096
#define QL_ROWS 16384

__global__ __launch_bounds__(256) void qlora_fused_kernel(
    const float* __restrict__ x,        // [ROWS, D]
    const int*   __restrict__ a_q,      // [2, D]
    const float* __restrict__ a_scale,  // [2]
    const int*   __restrict__ b_q,      // [D, 2]
    const float* __restrict__ b_scale,  // [D]
    float*       __restrict__ out)      // [ROWS, D]
{
    const int row = blockIdx.x;
    const int t   = threadIdx.x;

    const float* xr   = x   + (size_t)row * QL_D;
    float*       outr = out + (size_t)row * QL_D;

    // ---- Phase 1: partial dot products against int8 A rows (scale deferred)
    float h0 = 0.0f, h1 = 0.0f;
    const float4* xr4 = (const float4*)xr;
    const int4*   a0p = (const int4*)a_q;          // row 0
    const int4*   a1p = (const int4*)(a_q + QL_D); // row 1

#pragma unroll
    for (int k = 0; k < 4; ++k) {
        const int d4 = t + 256 * k;          // float4 index; d = 4*d4 .. 4*d4+3
        const float4 xv = xr4[d4];
        const int4   a0 = a0p[d4];
        const int4   a1 = a1p[d4];
        h0 += xv.x * (float)a0.x + xv.y * (float)a0.y
            + xv.z * (float)a0.z + xv.w * (float)a0.w;
        h1 += xv.x * (float)a1.x + xv.y * (float)a1.y
            + xv.z * (float)a1.z + xv.w * (float)a1.w;
    }

    // ---- Phase 2: wave-64 shuffle reduction, then cross-wave via LDS
#pragma unroll
    for (int off = 32; off > 0; off >>= 1) {
        h0 += __shfl_down(h0, off, 64);
        h1 += __shfl_down(h1, off, 64);
    }

    __shared__ float s0[4], s1[4];
    const int wave = t >> 6;
    const int lane = t & 63;
    if (lane == 0) { s0[wave] = h0; s1[wave] = h1; }
    __syncthreads();

    const float H0 = (s0[0] + s0[1] + s0[2] + s0[3]) * a_scale[0];
    const float H1 = (s1[0] + s1[1] + s1[2] + s1[3]) * a_scale[1];

    // ---- Phase 3: output row. B[d,r] = b_q[d,r] * b_scale[d]
    const int4*   bq4 = (const int4*)b_q;      // 2 d-entries per int4
    const float4* bs4 = (const float4*)b_scale;

#pragma unroll
    for (int k = 0; k < 4; ++k) {
        const int d4 = t + 256 * k;
        const float4 bs  = bs4[d4];
        const int4   bq0 = bq4[2 * d4];        // d = 4*d4, 4*d4+1
        const int4   bq1 = bq4[2 * d4 + 1];    // d = 4*d4+2, 4*d4+3
        float4 o;
        o.x = 0.5f * bs.x * (H0 * (float)bq0.x + H1 * (float)bq0.y);
        o.y = 0.5f * bs.y * (H0 * (float)bq0.z + H1 * (float)bq0.w);
        o.z = 0.5f * bs.z * (H0 * (float)bq1.x + H1 * (float)bq1.y);
        o.w = 0.5f * bs.w * (H0 * (float)bq1.z + H1 * (float)bq1.w);
        ((float4*)outr)[d4] = o;
    }
}

extern "C" void kernel_launch(void* const* d_in, const int* in_sizes, int n_in,
                              void* d_out, int out_size, void* d_ws, size_t ws_size,
                              hipStream_t stream) {
    const float* x       = (const float*)d_in[0];   // [4,4096,4096]
    const int*   a_q     = (const int*)d_in[1];     // [2,4096]
    const float* a_scale = (const float*)d_in[2];   // [2]
    const int*   b_q     = (const int*)d_in[3];     // [4096,2]
    const float* b_scale = (const float*)d_in[4];   // [4096]
    float*       out     = (float*)d_out;           // [4,4096,4096]

    qlora_fused_kernel<<<QL_ROWS, 256, 0, stream>>>(x, a_q, a_scale, b_q, b_scale, out);
}

// Round 2
// 451.121 us; speedup vs baseline: 1.0008x; 1.0008x over previous
//
#include <hip/hip_runtime.h>
#include <hip/hip_bf16.h>

// QLoRA rank-2, two-pass streaming formulation.
//   Pass 1: h[row] = (a_scale[r] * sum_d x[row,d]*a_q[r,d])  -> d_ws  (read-bound)
//   Pass 2: out[row,d] = 0.5*b_scale[d]*(h0*b_q[d,0]+h1*b_q[d,1])     (write-bound)
// Each block preloads its A/B fragment into registers once and reuses it
// across multiple rows (4 rows in pass 1, 8 rows in pass 2).

#define QL_D    4096
#define QL_ROWS 16384
#define K1_ROWS 4   // rows per block, pass 1
#define K2_ROWS 8   // rows per block, pass 2

__global__ __launch_bounds__(256) void qlora_h_kernel(
    const float* __restrict__ x,        // [ROWS, D]
    const int*   __restrict__ a_q,      // [2, D]
    const float* __restrict__ a_scale,  // [2]
    float2*      __restrict__ h_out)    // [ROWS]
{
    const int t    = threadIdx.x;
    const int row0 = blockIdx.x * K1_ROWS;

    // ---- Preload A fragment into registers (16 d-entries per thread, both ranks)
    float fa0[16], fa1[16];
    const int4* a0p = (const int4*)a_q;          // rank 0 row
    const int4* a1p = (const int4*)(a_q + QL_D); // rank 1 row
#pragma unroll
    for (int k = 0; k < 4; ++k) {
        const int4 q0 = a0p[t + 256 * k];
        const int4 q1 = a1p[t + 256 * k];
        fa0[4*k+0] = (float)q0.x; fa0[4*k+1] = (float)q0.y;
        fa0[4*k+2] = (float)q0.z; fa0[4*k+3] = (float)q0.w;
        fa1[4*k+0] = (float)q1.x; fa1[4*k+1] = (float)q1.y;
        fa1[4*k+2] = (float)q1.z; fa1[4*k+3] = (float)q1.w;
    }

    __shared__ float s0[K1_ROWS][4], s1[K1_ROWS][4];
    const int wave = t >> 6;
    const int lane = t & 63;

    const float4* x4 = (const float4*)(x + (size_t)row0 * QL_D);

#pragma unroll
    for (int r = 0; r < K1_ROWS; ++r) {
        float h0 = 0.0f, h1 = 0.0f;
#pragma unroll
        for (int k = 0; k < 4; ++k) {
            const float4 xv = x4[r * (QL_D / 4) + t + 256 * k];
            h0 += xv.x * fa0[4*k+0] + xv.y * fa0[4*k+1]
                + xv.z * fa0[4*k+2] + xv.w * fa0[4*k+3];
            h1 += xv.x * fa1[4*k+0] + xv.y * fa1[4*k+1]
                + xv.z * fa1[4*k+2] + xv.w * fa1[4*k+3];
        }
#pragma unroll
        for (int off = 32; off > 0; off >>= 1) {
            h0 += __shfl_down(h0, off, 64);
            h1 += __shfl_down(h1, off, 64);
        }
        if (lane == 0) { s0[r][wave] = h0; s1[r][wave] = h1; }
    }
    __syncthreads();

    if (t < K1_ROWS) {
        const float H0 = (s0[t][0] + s0[t][1] + s0[t][2] + s0[t][3]) * a_scale[0];
        const float H1 = (s1[t][0] + s1[t][1] + s1[t][2] + s1[t][3]) * a_scale[1];
        h_out[row0 + t] = make_float2(H0, H1);
    }
}

__global__ __launch_bounds__(256) void qlora_out_kernel(
    const float2* __restrict__ h_in,     // [ROWS]
    const int*    __restrict__ b_q,      // [D, 2]
    const float*  __restrict__ b_scale,  // [D]
    float*        __restrict__ out)      // [ROWS, D]
{
    const int t    = threadIdx.x;
    const int row0 = blockIdx.x * K2_ROWS;

    // ---- Preload dequantized B fragment into registers (16 d-entries/thread)
    // bb0[d] = 0.5*b_scale[d]*b_q[d,0], bb1[d] = 0.5*b_scale[d]*b_q[d,1]
    float bb0[16], bb1[16];
    const int4*   bq4 = (const int4*)b_q;     // 2 d-entries per int4
    const float4* bs4 = (const float4*)b_scale;
#pragma unroll
    for (int k = 0; k < 4; ++k) {
        const int d4 = t + 256 * k;
        const float4 bs = bs4[d4];
        const int4   q0 = bq4[2 * d4];
        const int4   q1 = bq4[2 * d4 + 1];
        bb0[4*k+0] = 0.5f * bs.x * (float)q0.x; bb1[4*k+0] = 0.5f * bs.x * (float)q0.y;
        bb0[4*k+1] = 0.5f * bs.y * (float)q0.z; bb1[4*k+1] = 0.5f * bs.y * (float)q0.w;
        bb0[4*k+2] = 0.5f * bs.z * (float)q1.x; bb1[4*k+2] = 0.5f * bs.z * (float)q1.y;
        bb0[4*k+3] = 0.5f * bs.w * (float)q1.z; bb1[4*k+3] = 0.5f * bs.w * (float)q1.w;
    }

    float4* o4 = (float4*)(out + (size_t)row0 * QL_D);

#pragma unroll 2
    for (int r = 0; r < K2_ROWS; ++r) {
        const float2 h = h_in[row0 + r];   // wave-uniform broadcast load
#pragma unroll
        for (int k = 0; k < 4; ++k) {
            float4 o;
            o.x = h.x * bb0[4*k+0] + h.y * bb1[4*k+0];
            o.y = h.x * bb0[4*k+1] + h.y * bb1[4*k+1];
            o.z = h.x * bb0[4*k+2] + h.y * bb1[4*k+2];
            o.w = h.x * bb0[4*k+3] + h.y * bb1[4*k+3];
            o4[r * (QL_D / 4) + t + 256 * k] = o;
        }
    }
}

extern "C" void kernel_launch(void* const* d_in, const int* in_sizes, int n_in,
                              void* d_out, int out_size, void* d_ws, size_t ws_size,
                              hipStream_t stream) {
    const float* x       = (const float*)d_in[0];   // [4,4096,4096]
    const int*   a_q     = (const int*)d_in[1];     // [2,4096]
    const float* a_scale = (const float*)d_in[2];   // [2]
    const int*   b_q     = (const int*)d_in[3];     // [4096,2]
    const float* b_scale = (const float*)d_in[4];   // [4096]
    float*       out     = (float*)d_out;           // [4,4096,4096]
    float2*      h_ws    = (float2*)d_ws;           // [16384] intermediate

    qlora_h_kernel  <<<QL_ROWS / K1_ROWS, 256, 0, stream>>>(x, a_q, a_scale, h_ws);
    qlora_out_kernel<<<QL_ROWS / K2_ROWS, 256, 0, stream>>>(h_ws, b_q, b_scale, out);
}